// Round 8
// baseline (283.129 us; speedup 1.0000x reference)
//
#include <hip/hip_runtime.h>
#include <cstdint>

#define NT 8192
#define DD 1024
#define NE 8
#define BK 64
#define NKIT (DD / BK)
#define TM 256                 // m-tile
#define MAXTILE 40             // sum ceil(c/256) <= 8192/256 + 8
#define TPX (MAXTILE / 8)      // tiles per XCD = 5
#define NBLK 4                 // n-blocks = DD/256

typedef __attribute__((ext_vector_type(8))) _Float16 half8;
typedef __attribute__((ext_vector_type(4))) float f32x4;

__device__ __forceinline__ unsigned short f2h_bits(float f) {
  _Float16 h = (_Float16)f;
  return __builtin_bit_cast(unsigned short, h);
}

// async global->LDS, 16B per lane. LDS dest must be wave-uniform base + lane*16;
// the GLOBAL address is an ordinary per-lane VGPR address (indirection is fine).
#define GLDS16(gp, lp) __builtin_amdgcn_global_load_lds( \
  (__attribute__((address_space(1))) void*)(uintptr_t)(gp), \
  (__attribute__((address_space(3))) void*)(uintptr_t)(lp), 16, 0, 0)

// s_waitcnt imm (gfx9): vmcnt[3:0]|[15:14], expcnt[6:4], lgkmcnt[11:8]; 0xF70|N = vmcnt(N) only
#define WAITCNT_VM0  0xF70

// ---------------- fused prep: wcast (blocks 0..4095) + gate (blocks 4096..5119) ----------------
__global__ __launch_bounds__(256) void prep_kernel(
    const float* __restrict__ W1, const float* __restrict__ W2,
    _Float16* __restrict__ W1t, _Float16* __restrict__ W2t,
    const float* __restrict__ x, const float* __restrict__ Wg, const float* __restrict__ bg,
    int* __restrict__ assign, float* __restrict__ wgt, _Float16* __restrict__ xh) {
  __shared__ alignas(16) char smem[32768];
  const int bid = blockIdx.x;
  const int tid = threadIdx.x;
  if (bid < 4096) {
    // ---- wcast path: fp32 [e][k][n] -> fp16 [e][n][k] ----
    float (*tile)[65] = (float (*)[65])smem;   // 64 x 65 floats = 16.6 KB
    const int z = bid >> 8;                    // 0..15: [0,8)=W1, [8,16)=W2
    const float* W = (z < 8 ? W1 : W2) + (size_t)(z & 7) * (DD * DD);
    _Float16* Wt   = (z < 8 ? W1t : W2t) + (size_t)(z & 7) * (DD * DD);
    const int k0 = (bid & 15) * 64, n0 = ((bid >> 4) & 15) * 64;
#pragma unroll
    for (int it = 0; it < 4; ++it) {
      int idx = it * 256 + tid;                // 0..1023
      int r = idx >> 4;                        // k-row 0..63
      int q = idx & 15;                        // float4 col
      float4 v = *(const float4*)(W + (size_t)(k0 + r) * DD + n0 + q * 4);
      tile[r][q * 4 + 0] = v.x; tile[r][q * 4 + 1] = v.y;
      tile[r][q * 4 + 2] = v.z; tile[r][q * 4 + 3] = v.w;
    }
    __syncthreads();
#pragma unroll
    for (int it = 0; it < 4; ++it) {
      int idx = it * 256 + tid;
      int n = idx >> 4;                        // out row (n) 0..63
      int q = idx & 15;                        // k 4-chunk
      ushort4 o;
      o.x = f2h_bits(tile[q * 4 + 0][n]);
      o.y = f2h_bits(tile[q * 4 + 1][n]);
      o.z = f2h_bits(tile[q * 4 + 2][n]);
      o.w = f2h_bits(tile[q * 4 + 3][n]);
      *(ushort4*)(Wt + (size_t)(n0 + n) * DD + k0 + q * 4) = o;
    }
  } else {
    // ---- gate path ----
    float* WgL = (float*)smem;                 // NE*DD floats = 32 KB, e-major
    const int gb = bid - 4096;                 // 0..1023
#pragma unroll
    for (int it = 0; it < 8; ++it) {
      int idx = it * 256 + tid;                // float4 index 0..2047
      float4 v = ((const float4*)Wg)[idx];
      int k = idx >> 1;
      int e0 = (idx & 1) * 4;
      WgL[(e0 + 0) * DD + k] = v.x;
      WgL[(e0 + 1) * DD + k] = v.y;
      WgL[(e0 + 2) * DD + k] = v.z;
      WgL[(e0 + 3) * DD + k] = v.w;
    }
    __syncthreads();
    const int lane = tid & 63, w = tid >> 6;
#pragma unroll
    for (int s = 0; s < 2; ++s) {
      const int t = gb * 8 + w * 2 + s;
      const float4* xr = (const float4*)(x + (size_t)t * DD);
      float4 xv[4];
#pragma unroll
      for (int c = 0; c < 4; ++c) xv[c] = xr[lane + 64 * c];
      ushort4* xo = (ushort4*)(xh + (size_t)t * DD);
#pragma unroll
      for (int c = 0; c < 4; ++c) {
        union { ushort4 u; _Float16 h[4]; } cv;
        cv.h[0] = (_Float16)xv[c].x; cv.h[1] = (_Float16)xv[c].y;
        cv.h[2] = (_Float16)xv[c].z; cv.h[3] = (_Float16)xv[c].w;
        xo[lane + 64 * c] = cv.u;
      }
      float p[NE];
#pragma unroll
      for (int e = 0; e < NE; ++e) {
        float acc = 0.f;
#pragma unroll
        for (int c = 0; c < 4; ++c) {
          float4 wv = *(const float4*)&WgL[e * DD + 4 * lane + 256 * c];
          acc += xv[c].x * wv.x + xv[c].y * wv.y + xv[c].z * wv.z + xv[c].w * wv.w;
        }
        p[e] = acc;
      }
#pragma unroll
      for (int e = 0; e < NE; ++e) {
        float v = p[e];
        for (int off = 32; off > 0; off >>= 1) v += __shfl_down(v, off, 64);
        p[e] = v;
      }
      if (lane == 0) {
        float l[NE];
#pragma unroll
        for (int e = 0; e < NE; ++e) l[e] = p[e] + bg[e];
        int a = 0; float best = l[0];
#pragma unroll
        for (int e = 1; e < NE; ++e) if (l[e] > best) { best = l[e]; a = e; }
        float sum = 0.f;
#pragma unroll
        for (int e = 0; e < NE; ++e) sum += expf(l[e] - best);
        assign[t] = a;
        wgt[t] = 1.0f / sum;
      }
    }
  }
}

// ---------------- sort: deterministic counting sort + tile plan (256-row tiles) ----------------
__global__ __launch_bounds__(1024) void sort_kernel(
    const int* __restrict__ assign, int* __restrict__ rowtok, int* __restrict__ plan) {
  __shared__ int sc[NE * 1024];            // 32 KB, e-major
  __shared__ int s_pref[NE + 1];
  const int tid = threadIdx.x;
  int a[8];
  int c[NE];
#pragma unroll
  for (int e = 0; e < NE; ++e) c[e] = 0;
#pragma unroll
  for (int j = 0; j < 8; ++j) { a[j] = assign[tid * 8 + j]; ++c[a[j]]; }
#pragma unroll
  for (int e = 0; e < NE; ++e) sc[e * 1024 + tid] = c[e];
  __syncthreads();
  for (int d = 1; d < 1024; d <<= 1) {
    int add[NE];
    if (tid >= d) {
#pragma unroll
      for (int e = 0; e < NE; ++e) add[e] = sc[e * 1024 + tid - d];
    }
    __syncthreads();
    if (tid >= d) {
#pragma unroll
      for (int e = 0; e < NE; ++e) sc[e * 1024 + tid] += add[e];
    }
    __syncthreads();
  }
  int tot[NE], incl[NE];
#pragma unroll
  for (int e = 0; e < NE; ++e) { tot[e] = sc[e * 1024 + 1023]; incl[e] = sc[e * 1024 + tid]; }
  int offs[NE];
  {
    int s = 0;
#pragma unroll
    for (int e = 0; e < NE; ++e) { offs[e] = s; s += tot[e]; }
  }
  int run[NE];
#pragma unroll
  for (int e = 0; e < NE; ++e) run[e] = offs[e] + incl[e] - c[e];
#pragma unroll
  for (int j = 0; j < 8; ++j) { int e = a[j]; rowtok[run[e]++] = tid * 8 + j; }
  // parallel tile-plan build
  if (tid == 0) {
    int s = 0;
    for (int e = 0; e < NE; ++e) { s_pref[e] = s; s += (tot[e] + TM - 1) / TM; }
    s_pref[NE] = s;
    plan[0] = s;
  }
  __syncthreads();
  const int nt = s_pref[NE];
  if (tid < nt) {
    int e = 0;
    while (tid >= s_pref[e + 1]) ++e;
    int t = tid - s_pref[e];
    plan[1 + tid] = e;
    plan[1 + MAXTILE + tid] = offs[e] + t * TM;
    plan[1 + 2 * MAXTILE + tid] = offs[e] + tot[e];
  }
}

// ---------------- grouped GEMM: 256x256 tile, BK=64, 8 waves (128x64 each), 2-buffer ----------------
// R7 post-mortem: 7 variants of 128-tile geometry all pinned at 46-55us (~354 TF). learn_hip
// m248v2 measured THIS problem shape (grouped, 256^2 tile, K=1024) at 666 TF with the same
// simple 2-phase loop -> the gap is geometry, not schedule. R8: port to the proven 256^2
// operating point: 512 threads, 8 waves in 2m x 4n, wave tile 128x64 (acc 8x4 = 128 VGPR),
// 64 MFMA per 24 ds_read_b128 per wave-iter (2.67 ratio), LDS 2 x (A 32KB + B 32KB) = 128KB
// -> 1 block/CU. Same R7 schedule: STAGE(next) -> COMPUTE(cur) -> vmcnt(0) -> barrier.
// Same XOR chunk swizzle (conflict-free). XCD map: 160 blocks = 8 XCDs x 5 tiles x 4 nb.
// MODE 0: H[p] = gelu_exact(xh[rowtok[p]] @ W1t^T + b1)  -> fp16
// MODE 1: out[rowtok[p]] = (H[p] @ W2t^T + b2) * wgt      -> fp32 scatter
template <int MODE>
__global__ __launch_bounds__(512, 2) void gemm_kernel(
    const _Float16* __restrict__ A,
    const _Float16* __restrict__ Wt,
    const float* __restrict__ bias,
    const int* __restrict__ plan,
    _Float16* __restrict__ Hout,
    float* __restrict__ Fout,
    const int* __restrict__ rowtok,
    const float* __restrict__ wgt) {
  const int wrk = blockIdx.x;
  // XCD-aware bijection: g = XCD (bid%8 round-robin), r = rank within XCD (0..19).
  const int g = wrk & 7;
  const int r = wrk >> 3;
  const int tile = g * TPX + (r >> 2);
  const int nb = r & 3;
  if (tile >= plan[0]) return;
  const int e = plan[1 + tile];
  const int m0 = plan[1 + MAXTILE + tile];
  const int seg_end = plan[1 + 2 * MAXTILE + tile];
  const int n0 = nb * 256;

  const int tid = threadIdx.x;
  const int lane = tid & 63;
  const int wv = tid >> 6;             // wave 0..7
  const int wm = wv >> 2;              // m half 0..1 (128 rows)
  const int wn = wv & 3;               // n quarter 0..3 (64 cols)
  const int quad = lane >> 4;
  const int r15 = lane & 15;

  // LDS: 2 buffers x (A 32KB + B 32KB) = 128 KB -> 1 block/CU
  __shared__ alignas(16) char lds[131072];

  // staging: tile 256 rows x 64 halves (32 KB) = 2048 slots of 16B over 512 threads
  // (4 slots/thread). slot -> row = slot>>3, stored chunk sc = slot&7,
  // logical chunk c = sc ^ (row&7)  (chunk = 8 halves = 16B).
  const _Float16* We = Wt + (size_t)e * DD * DD;
  const _Float16* gAp[4];
  const _Float16* gBp[4];
  int ldso[4];
#pragma unroll
  for (int i = 0; i < 4; ++i) {
    int slot = i * 512 + tid;
    int row = slot >> 3;               // 0..255
    int c = (slot & 7) ^ (row & 7);
    int rg = m0 + row; if (rg > NT - 1) rg = NT - 1;
    int arow = (MODE == 0) ? rowtok[rg] : rg;
    gAp[i] = A + (size_t)arow * DD + c * 8;
    gBp[i] = We + (size_t)(n0 + row) * DD + c * 8;
    ldso[i] = slot * 16;
  }

  // fragment read offsets (half8 units): row*8 + ((q*4 + quad) ^ (row&7)), q = k-sub 0..1
  // (row&7 == r15&7 since wm*128, wn*64, i*16 are all 0 mod 8)
  int aoff[8][2], boff[4][2];
#pragma unroll
  for (int i = 0; i < 8; ++i)
#pragma unroll
    for (int q = 0; q < 2; ++q) {
      int m = wm * 128 + i * 16 + r15;
      aoff[i][q] = m * 8 + ((q * 4 + quad) ^ (r15 & 7));
    }
#pragma unroll
  for (int i = 0; i < 4; ++i)
#pragma unroll
    for (int q = 0; q < 2; ++q) {
      int n = wn * 64 + i * 16 + r15;
      boff[i][q] = n * 8 + ((q * 4 + quad) ^ (r15 & 7));
    }

  f32x4 acc[8][4];
  f32x4 zero4 = {0.f, 0.f, 0.f, 0.f};
#pragma unroll
  for (int mi = 0; mi < 8; ++mi)
#pragma unroll
    for (int ni = 0; ni < 4; ++ni) acc[mi][ni] = zero4;

#define LDSBUF(B) (lds + (B) * 65536)
#define STAGE(KT, BUF) do {                                          \
    const int ko_ = (KT) * BK;                                       \
    char* lb_ = LDSBUF(BUF);                                         \
    GLDS16(gAp[0] + ko_, lb_ + ldso[0]);                             \
    GLDS16(gAp[1] + ko_, lb_ + ldso[1]);                             \
    GLDS16(gAp[2] + ko_, lb_ + ldso[2]);                             \
    GLDS16(gAp[3] + ko_, lb_ + ldso[3]);                             \
    GLDS16(gBp[0] + ko_, lb_ + 32768 + ldso[0]);                     \
    GLDS16(gBp[1] + ko_, lb_ + 32768 + ldso[1]);                     \
    GLDS16(gBp[2] + ko_, lb_ + 32768 + ldso[2]);                     \
    GLDS16(gBp[3] + ko_, lb_ + 32768 + ldso[3]);                     \
  } while (0)
#define COMPUTE(BUF) do {                                            \
    const half8* AsV = (const half8*)(LDSBUF(BUF));                  \
    const half8* BsV = (const half8*)(LDSBUF(BUF) + 32768);          \
    _Pragma("unroll")                                                \
    for (int q = 0; q < 2; ++q) {                                    \
      half8 b_[4];                                                   \
      _Pragma("unroll")                                              \
      for (int i = 0; i < 4; ++i) b_[i] = BsV[boff[i][q]];           \
      _Pragma("unroll")                                              \
      for (int mi = 0; mi < 8; ++mi) {                               \
        half8 a_ = AsV[aoff[mi][q]];                                 \
        _Pragma("unroll")                                            \
        for (int ni = 0; ni < 4; ++ni)                               \
          acc[mi][ni] = __builtin_amdgcn_mfma_f32_16x16x32_f16(a_, b_[ni], acc[mi][ni], 0, 0, 0); \
      }                                                              \
    }                                                                \
  } while (0)

  // prologue: fill buffer 0, make visible
  STAGE(0, 0);
  __builtin_amdgcn_s_waitcnt(WAITCNT_VM0);
  __builtin_amdgcn_s_barrier();
  __asm__ volatile("" ::: "memory");

#pragma unroll 1
  for (int kt = 0; kt < NKIT; ++kt) {
    const int buf = kt & 1;
    if (kt + 1 < NKIT) STAGE(kt + 1, buf ^ 1);   // issue next-tile loads first
    COMPUTE(buf);                                // compute current (hides load latency)
    __builtin_amdgcn_s_waitcnt(WAITCNT_VM0);     // next tile landed
    __builtin_amdgcn_s_barrier();                // visible to all; buf free for re-stage
    __asm__ volatile("" ::: "memory");
  }
#undef COMPUTE
#undef STAGE
#undef LDSBUF

  // epilogue. C/D layout: col = lane&15, row = quad*4 + reg
  const float* bptr = bias + (size_t)e * DD;
#pragma unroll
  for (int mi = 0; mi < 8; ++mi) {
    int rowb = m0 + wm * 128 + mi * 16 + quad * 4;
#pragma unroll
    for (int rr = 0; rr < 4; ++rr) {
      int gpos = rowb + rr;
      if (gpos < seg_end) {
        if (MODE == 0) {
#pragma unroll
          for (int ni = 0; ni < 4; ++ni) {
            int n = n0 + wn * 64 + ni * 16 + r15;
            float val = acc[mi][ni][rr] + bptr[n];
            val = 0.5f * val * (1.0f + erff(val * 0.70710678118654752f));
            Hout[(size_t)gpos * DD + n] = (_Float16)val;
          }
        } else {
          int tok = rowtok[gpos];
          float wgl = wgt[tok];
          float* orow = Fout + (size_t)tok * DD;
#pragma unroll
          for (int ni = 0; ni < 4; ++ni) {
            int n = n0 + wn * 64 + ni * 16 + r15;
            orow[n] = (acc[mi][ni][rr] + bptr[n]) * wgl;
          }
        }
      }
    }
  }
}

extern "C" void kernel_launch(void* const* d_in, const int* in_sizes, int n_in,
                              void* d_out, int out_size, void* d_ws, size_t ws_size,
                              hipStream_t stream) {
  const float* x  = (const float*)d_in[0];
  const float* Wg = (const float*)d_in[1];
  const float* bg = (const float*)d_in[2];
  const float* W1 = (const float*)d_in[3];
  const float* b1 = (const float*)d_in[4];
  const float* W2 = (const float*)d_in[5];
  const float* b2 = (const float*)d_in[6];
  float* out = (float*)d_out;

  char* ws = (char*)d_ws;
  const size_t MB16 = (size_t)1 << 24;
  _Float16* W1t = (_Float16*)(ws + 0 * MB16);
  _Float16* W2t = (_Float16*)(ws + 1 * MB16);
  _Float16* xh  = (_Float16*)(ws + 2 * MB16);
  _Float16* H   = (_Float16*)(ws + 3 * MB16);
  int*   assign = (int*)(ws + 4 * MB16);
  int*   rowtok = assign + NT;
  float* wgt    = (float*)(rowtok + NT);
  int*   plan   = (int*)(wgt + NT);    // [1 + 3*MAXTILE]

  prep_kernel<<<4096 + NT / 8, 256, 0, stream>>>(W1, W2, W1t, W2t, x, Wg, bg, assign, wgt, xh);
  sort_kernel<<<1, 1024, 0, stream>>>(assign, rowtok, plan);
  gemm_kernel<0><<<MAXTILE * NBLK, 512, 0, stream>>>(xh, W1t, b1, plan, H, nullptr, rowtok, nullptr);
  gemm_kernel<1><<<MAXTILE * NBLK, 512, 0, stream>>>(H, W2t, b2, plan, nullptr, out, rowtok, wgt);
}

// Round 9
// 229.193 us; speedup vs baseline: 1.2353x; 1.2353x over previous
//
#include <hip/hip_runtime.h>
#include <cstdint>

#define NT 8192
#define DD 1024
#define NE 8
#define BK 32
#define NKIT (DD / BK)
#define TM 128                 // m-tile
#define MAXTILE 72             // sum ceil(c/128) <= 8192/128 + 8
#define TPX (MAXTILE / 8)      // tiles per XCD = 9

typedef __attribute__((ext_vector_type(8))) _Float16 half8;
typedef __attribute__((ext_vector_type(4))) float f32x4;

__device__ __forceinline__ unsigned short f2h_bits(float f) {
  _Float16 h = (_Float16)f;
  return __builtin_bit_cast(unsigned short, h);
}

// async global->LDS, 16B per lane. LDS dest must be wave-uniform base + lane*16;
// the GLOBAL address is an ordinary per-lane VGPR address (indirection is fine).
#define GLDS16(gp, lp) __builtin_amdgcn_global_load_lds( \
  (__attribute__((address_space(1))) void*)(uintptr_t)(gp), \
  (__attribute__((address_space(3))) void*)(uintptr_t)(lp), 16, 0, 0)

// s_waitcnt imm (gfx9): vmcnt[3:0]|[15:14], expcnt[6:4], lgkmcnt[11:8]; 0xF70|N = vmcnt(N) only
#define WAITCNT_VM4  0xF74
#define WAITCNT_VM0  0xF70

// ---------------- fused prep: wcast (blocks 0..4095) + gate (blocks 4096..5119) ----------------
__global__ __launch_bounds__(256) void prep_kernel(
    const float* __restrict__ W1, const float* __restrict__ W2,
    _Float16* __restrict__ W1t, _Float16* __restrict__ W2t,
    const float* __restrict__ x, const float* __restrict__ Wg, const float* __restrict__ bg,
    int* __restrict__ assign, float* __restrict__ wgt, _Float16* __restrict__ xh) {
  __shared__ alignas(16) char smem[32768];
  const int bid = blockIdx.x;
  const int tid = threadIdx.x;
  if (bid < 4096) {
    // ---- wcast path: fp32 [e][k][n] -> fp16 [e][n][k] ----
    float (*tile)[65] = (float (*)[65])smem;   // 64 x 65 floats = 16.6 KB
    const int z = bid >> 8;                    // 0..15: [0,8)=W1, [8,16)=W2
    const float* W = (z < 8 ? W1 : W2) + (size_t)(z & 7) * (DD * DD);
    _Float16* Wt   = (z < 8 ? W1t : W2t) + (size_t)(z & 7) * (DD * DD);
    const int k0 = (bid & 15) * 64, n0 = ((bid >> 4) & 15) * 64;
#pragma unroll
    for (int it = 0; it < 4; ++it) {
      int idx = it * 256 + tid;                // 0..1023
      int r = idx >> 4;                        // k-row 0..63
      int q = idx & 15;                        // float4 col
      float4 v = *(const float4*)(W + (size_t)(k0 + r) * DD + n0 + q * 4);
      tile[r][q * 4 + 0] = v.x; tile[r][q * 4 + 1] = v.y;
      tile[r][q * 4 + 2] = v.z; tile[r][q * 4 + 3] = v.w;
    }
    __syncthreads();
#pragma unroll
    for (int it = 0; it < 4; ++it) {
      int idx = it * 256 + tid;
      int n = idx >> 4;                        // out row (n) 0..63
      int q = idx & 15;                        // k 4-chunk
      ushort4 o;
      o.x = f2h_bits(tile[q * 4 + 0][n]);
      o.y = f2h_bits(tile[q * 4 + 1][n]);
      o.z = f2h_bits(tile[q * 4 + 2][n]);
      o.w = f2h_bits(tile[q * 4 + 3][n]);
      *(ushort4*)(Wt + (size_t)(n0 + n) * DD + k0 + q * 4) = o;
    }
  } else {
    // ---- gate path ----
    float* WgL = (float*)smem;                 // NE*DD floats = 32 KB, e-major
    const int gb = bid - 4096;                 // 0..1023
#pragma unroll
    for (int it = 0; it < 8; ++it) {
      int idx = it * 256 + tid;                // float4 index 0..2047
      float4 v = ((const float4*)Wg)[idx];
      int k = idx >> 1;
      int e0 = (idx & 1) * 4;
      WgL[(e0 + 0) * DD + k] = v.x;
      WgL[(e0 + 1) * DD + k] = v.y;
      WgL[(e0 + 2) * DD + k] = v.z;
      WgL[(e0 + 3) * DD + k] = v.w;
    }
    __syncthreads();
    const int lane = tid & 63, w = tid >> 6;
#pragma unroll
    for (int s = 0; s < 2; ++s) {
      const int t = gb * 8 + w * 2 + s;
      const float4* xr = (const float4*)(x + (size_t)t * DD);
      float4 xv[4];
#pragma unroll
      for (int c = 0; c < 4; ++c) xv[c] = xr[lane + 64 * c];
      ushort4* xo = (ushort4*)(xh + (size_t)t * DD);
#pragma unroll
      for (int c = 0; c < 4; ++c) {
        union { ushort4 u; _Float16 h[4]; } cv;
        cv.h[0] = (_Float16)xv[c].x; cv.h[1] = (_Float16)xv[c].y;
        cv.h[2] = (_Float16)xv[c].z; cv.h[3] = (_Float16)xv[c].w;
        xo[lane + 64 * c] = cv.u;
      }
      float p[NE];
#pragma unroll
      for (int e = 0; e < NE; ++e) {
        float acc = 0.f;
#pragma unroll
        for (int c = 0; c < 4; ++c) {
          float4 wv = *(const float4*)&WgL[e * DD + 4 * lane + 256 * c];
          acc += xv[c].x * wv.x + xv[c].y * wv.y + xv[c].z * wv.z + xv[c].w * wv.w;
        }
        p[e] = acc;
      }
#pragma unroll
      for (int e = 0; e < NE; ++e) {
        float v = p[e];
        for (int off = 32; off > 0; off >>= 1) v += __shfl_down(v, off, 64);
        p[e] = v;
      }
      if (lane == 0) {
        float l[NE];
#pragma unroll
        for (int e = 0; e < NE; ++e) l[e] = p[e] + bg[e];
        int a = 0; float best = l[0];
#pragma unroll
        for (int e = 1; e < NE; ++e) if (l[e] > best) { best = l[e]; a = e; }
        float sum = 0.f;
#pragma unroll
        for (int e = 0; e < NE; ++e) sum += expf(l[e] - best);
        assign[t] = a;
        wgt[t] = 1.0f / sum;
      }
    }
  }
}

// ---------------- sort: shuffle-scan counting sort + tile plan (128-row tiles) ----------------
// R9: old Hillis-Steele version = 10 rounds x 2 barriers x 16K LDS ops on ONE CU (~15us on
// the critical path between prep and gemm0). New: per-wave register scan via __shfl_up
// (6 steps, no LDS), 16 wave-totals scanned by wave 0, 2 barriers total. Same deterministic
// token order (global exclusive prefix per expert, thread-major).
__global__ __launch_bounds__(1024) void sort_kernel(
    const int* __restrict__ assign, int* __restrict__ rowtok, int* __restrict__ plan) {
  __shared__ int wsum[16][NE];
  __shared__ int wbase[16][NE];
  __shared__ int s_offs[NE];
  __shared__ int s_tot[NE];
  __shared__ int s_pref[NE + 1];
  const int tid = threadIdx.x;
  const int lane = tid & 63, wv = tid >> 6;   // 16 waves
  int a[8];
  int c[NE];
#pragma unroll
  for (int e = 0; e < NE; ++e) c[e] = 0;
#pragma unroll
  for (int j = 0; j < 8; ++j) { a[j] = assign[tid * 8 + j]; ++c[a[j]]; }
  // inclusive scan across the wave, per expert (registers only)
  int inc[NE];
#pragma unroll
  for (int e = 0; e < NE; ++e) inc[e] = c[e];
  for (int d = 1; d < 64; d <<= 1) {
#pragma unroll
    for (int e = 0; e < NE; ++e) {
      int u = __shfl_up(inc[e], d, 64);
      if (lane >= d) inc[e] += u;
    }
  }
  if (lane == 63) {
#pragma unroll
    for (int e = 0; e < NE; ++e) wsum[wv][e] = inc[e];
  }
  __syncthreads();
  // wave 0, lanes 0..15: scan wave totals, compute expert offsets + plan
  if (wv == 0 && lane < 16) {
    int v[NE], incw[NE];
#pragma unroll
    for (int e = 0; e < NE; ++e) { v[e] = wsum[lane][e]; incw[e] = v[e]; }
    for (int d = 1; d < 16; d <<= 1) {
#pragma unroll
      for (int e = 0; e < NE; ++e) {
        int u = __shfl_up(incw[e], d, 64);
        if (lane >= d) incw[e] += u;
      }
    }
    int tote[NE];
#pragma unroll
    for (int e = 0; e < NE; ++e) tote[e] = __shfl(incw[e], 15, 64);
    int offs[NE];
    {
      int s = 0;
#pragma unroll
      for (int e = 0; e < NE; ++e) { offs[e] = s; s += tote[e]; }
    }
#pragma unroll
    for (int e = 0; e < NE; ++e) wbase[lane][e] = offs[e] + incw[e] - v[e];
    if (lane == 0) {
      int s = 0;
#pragma unroll
      for (int e = 0; e < NE; ++e) {
        s_offs[e] = offs[e]; s_tot[e] = tote[e];
        s_pref[e] = s; s += (tote[e] + TM - 1) / TM;
      }
      s_pref[NE] = s;
      plan[0] = s;
    }
  }
  __syncthreads();
  int run[NE];
#pragma unroll
  for (int e = 0; e < NE; ++e) run[e] = wbase[wv][e] + inc[e] - c[e];
#pragma unroll
  for (int j = 0; j < 8; ++j) { int e = a[j]; rowtok[run[e]++] = tid * 8 + j; }
  const int nt = s_pref[NE];
  if (tid < nt) {
    int e = 0;
    while (tid >= s_pref[e + 1]) ++e;
    int t = tid - s_pref[e];
    plan[1 + tid] = e;
    plan[1 + MAXTILE + tid] = s_offs[e] + t * TM;
    plan[1 + 2 * MAXTILE + tid] = s_offs[e] + s_tot[e];
  }
}

// ---------------- grouped GEMM: 128x128 tile, 4 waves (64x64 each), 3-buffer depth-2 ----------------
// R8 post-mortem: 256^2 tile -> only 160 blocks (1/CU), 96 CUs idle, no inter-block overlap
// at the vmcnt(0) drain -> 109us. Geometry ladder closed: this R5 config (46-48.5us, XCD
// swizzle FETCH 75->22MB) is the grouped-GEMM optimum for this problem's shape (N=1024,
// segmented M). Restored verbatim.
// MODE 0: H[p] = gelu_exact(xh[rowtok[p]] @ W1t^T + b1)  -> fp16
// MODE 1: out[rowtok[p]] = (H[p] @ W2t^T + b2) * wgt      -> fp32 scatter
template <int MODE>
__global__ __launch_bounds__(256, 3) void gemm_kernel(
    const _Float16* __restrict__ A,
    const _Float16* __restrict__ Wt,
    const float* __restrict__ bias,
    const int* __restrict__ plan,
    _Float16* __restrict__ Hout,
    float* __restrict__ Fout,
    const int* __restrict__ rowtok,
    const float* __restrict__ wgt) {
  const int wrk = blockIdx.x;
  // XCD-aware bijection: g = XCD (bid%8 round-robin), r = rank within XCD.
  const int g = wrk & 7;
  const int r = wrk >> 3;             // 0..71
  const int tile = g * TPX + (r >> 3);
  const int nb = r & 7;
  if (tile >= plan[0]) return;
  const int e = plan[1 + tile];
  const int m0 = plan[1 + MAXTILE + tile];
  const int seg_end = plan[1 + 2 * MAXTILE + tile];
  const int n0 = nb * 128;

  const int tid = threadIdx.x;
  const int lane = tid & 63;
  const int wv = tid >> 6;             // wave 0..3
  const int wm = wv >> 1;              // m half 0..1 (64 rows)
  const int wq = wv & 1;               // n half 0..1 (64 cols)
  const int quad = lane >> 4;
  const int r15 = lane & 15;

  // LDS: 3 buffers x (A 8KB + B 8KB) = 48 KB -> 3 blocks/CU
  __shared__ alignas(16) char lds[49152];

  // staging: A-tile 128 rows x 32 halves (8 KB) = 512 slots of 16B over 256 threads
  // (2 slots/thread: tid, tid+256). Same for B. slot -> row = slot>>2, stored chunk
  // sc = slot&3, logical chunk c = sc ^ ((row>>1)&3)  (chunk = 8 halves = 16B).
  const _Float16* We = Wt + (size_t)e * DD * DD;
  const _Float16* gAp[2];
  const _Float16* gBp[2];
  int ldsoA[2], ldsoB[2];
#pragma unroll
  for (int i = 0; i < 2; ++i) {
    int slot = i * 256 + tid;
    int row = slot >> 2;               // 0..127
    int c = (slot & 3) ^ ((row >> 1) & 3);
    int rg = m0 + row; if (rg > NT - 1) rg = NT - 1;
    int arow = (MODE == 0) ? rowtok[rg] : rg;
    gAp[i] = A + (size_t)arow * DD + c * 8;
    ldsoA[i] = slot * 16;
    gBp[i] = We + (size_t)(n0 + row) * DD + c * 8;
    ldsoB[i] = slot * 16;
  }

  // fragment read offsets (half8 units): row*4 + (quad ^ ((row>>1)&3))
  int aoff[4], boff[4];
#pragma unroll
  for (int i = 0; i < 4; ++i) {
    int m = wm * 64 + i * 16 + r15;
    aoff[i] = m * 4 + (quad ^ ((m >> 1) & 3));
    int n = wq * 64 + i * 16 + r15;
    boff[i] = n * 4 + (quad ^ ((n >> 1) & 3));
  }

  f32x4 acc[4][4];
  f32x4 zero4 = {0.f, 0.f, 0.f, 0.f};
#pragma unroll
  for (int mi = 0; mi < 4; ++mi)
#pragma unroll
    for (int ni = 0; ni < 4; ++ni) acc[mi][ni] = zero4;

#define LDSBUF(B) (lds + (B) * 16384)
#define STAGE(KT, BUF) do {                                          \
    const int ko_ = (KT) * BK;                                       \
    char* lb_ = LDSBUF(BUF);                                         \
    GLDS16(gAp[0] + ko_, lb_ + ldsoA[0]);                            \
    GLDS16(gAp[1] + ko_, lb_ + ldsoA[1]);                            \
    GLDS16(gBp[0] + ko_, lb_ + 8192 + ldsoB[0]);                     \
    GLDS16(gBp[1] + ko_, lb_ + 8192 + ldsoB[1]);                     \
  } while (0)
#define COMPUTE(BUF) do {                                            \
    const half8* AsV = (const half8*)(LDSBUF(BUF));                  \
    const half8* BsV = (const half8*)(LDSBUF(BUF) + 8192);           \
    half8 a_[4], b_[4];                                              \
    _Pragma("unroll")                                                \
    for (int i = 0; i < 4; ++i) a_[i] = AsV[aoff[i]];                \
    _Pragma("unroll")                                                \
    for (int i = 0; i < 4; ++i) b_[i] = BsV[boff[i]];                \
    _Pragma("unroll")                                                \
    for (int mi = 0; mi < 4; ++mi)                                   \
      _Pragma("unroll")                                              \
      for (int ni = 0; ni < 4; ++ni)                                 \
        acc[mi][ni] = __builtin_amdgcn_mfma_f32_16x16x32_f16(a_[mi], b_[ni], acc[mi][ni], 0, 0, 0); \
  } while (0)

  STAGE(0, 0);                         // prologue: fill 2 buffers (8 loads in flight)
  STAGE(1, 1);

  // stage s -> buf s%3 ; compute kt -> buf kt%3. Loop does 30 computes, unrolled x3.
#pragma unroll 1
  for (int kt = 0; kt < NKIT - 2; kt += 3) {
    __builtin_amdgcn_s_waitcnt(WAITCNT_VM4);   // own 4 loads of buf kt landed; kt+1 in flight
    __builtin_amdgcn_s_barrier();
    __asm__ volatile("" ::: "memory");
    STAGE(kt + 2, 2);
    COMPUTE(0);
    __builtin_amdgcn_s_waitcnt(WAITCNT_VM4);
    __builtin_amdgcn_s_barrier();
    __asm__ volatile("" ::: "memory");
    STAGE(kt + 3, 0);
    COMPUTE(1);
    __builtin_amdgcn_s_waitcnt(WAITCNT_VM4);
    __builtin_amdgcn_s_barrier();
    __asm__ volatile("" ::: "memory");
    STAGE(kt + 4, 1);
    COMPUTE(2);
  }
  // tail: computes NKIT-2 (buf 0), NKIT-1 (buf 1); nothing more staged
  __builtin_amdgcn_s_waitcnt(WAITCNT_VM4);
  __builtin_amdgcn_s_barrier();
  __asm__ volatile("" ::: "memory");
  COMPUTE(0);
  __builtin_amdgcn_s_waitcnt(WAITCNT_VM0);
  __builtin_amdgcn_s_barrier();
  __asm__ volatile("" ::: "memory");
  COMPUTE(1);
#undef COMPUTE
#undef STAGE
#undef LDSBUF

  // epilogue. C/D layout: col = lane&15, row = quad*4 + reg
  const float* bptr = bias + (size_t)e * DD;
#pragma unroll
  for (int mi = 0; mi < 4; ++mi) {
    int rowb = m0 + wm * 64 + mi * 16 + quad * 4;
#pragma unroll
    for (int rr = 0; rr < 4; ++rr) {
      int gpos = rowb + rr;
      if (gpos < seg_end) {
        if (MODE == 0) {
#pragma unroll
          for (int ni = 0; ni < 4; ++ni) {
            int n = n0 + wq * 64 + ni * 16 + r15;
            float val = acc[mi][ni][rr] + bptr[n];
            val = 0.5f * val * (1.0f + erff(val * 0.70710678118654752f));
            Hout[(size_t)gpos * DD + n] = (_Float16)val;
          }
        } else {
          int tok = rowtok[gpos];
          float wgl = wgt[tok];
          float* orow = Fout + (size_t)tok * DD;
#pragma unroll
          for (int ni = 0; ni < 4; ++ni) {
            int n = n0 + wq * 64 + ni * 16 + r15;
            orow[n] = (acc[mi][ni][rr] + bptr[n]) * wgl;
          }
        }
      }
    }
  }
}

extern "C" void kernel_launch(void* const* d_in, const int* in_sizes, int n_in,
                              void* d_out, int out_size, void* d_ws, size_t ws_size,
                              hipStream_t stream) {
  const float* x  = (const float*)d_in[0];
  const float* Wg = (const float*)d_in[1];
  const float* bg = (const float*)d_in[2];
  const float* W1 = (const float*)d_in[3];
  const float* b1 = (const float*)d_in[4];
  const float* W2 = (const float*)d_in[5];
  const float* b2 = (const float*)d_in[6];
  float* out = (float*)d_out;

  char* ws = (char*)d_ws;
  const size_t MB16 = (size_t)1 << 24;
  _Float16* W1t = (_Float16*)(ws + 0 * MB16);
  _Float16* W2t = (_Float16*)(ws + 1 * MB16);
  _Float16* xh  = (_Float16*)(ws + 2 * MB16);
  _Float16* H   = (_Float16*)(ws + 3 * MB16);
  int*   assign = (int*)(ws + 4 * MB16);
  int*   rowtok = assign + NT;
  float* wgt    = (float*)(rowtok + NT);
  int*   plan   = (int*)(wgt + NT);    // [1 + 3*MAXTILE]

  prep_kernel<<<4096 + NT / 8, 256, 0, stream>>>(W1, W2, W1t, W2t, x, Wg, bg, assign, wgt, xh);
  sort_kernel<<<1, 1024, 0, stream>>>(assign, rowtok, plan);
  gemm_kernel<0><<<MAXTILE * 8, 256, 0, stream>>>(xh, W1t, b1, plan, H, nullptr, rowtok, nullptr);
  gemm_kernel<1><<<MAXTILE * 8, 256, 0, stream>>>(H, W2t, b2, plan, nullptr, out, rowtok, wgt);
}